// Round 3
// baseline (211.616 us; speedup 1.0000x reference)
//
#include <hip/hip_runtime.h>
#include <hip/hip_bf16.h>

typedef __attribute__((ext_vector_type(8))) short short8;
typedef __attribute__((ext_vector_type(4))) float floatx4;

#define B_SZ   32
#define L_IN   8192
#define C_INCH 64
#define KW     3
#define F_OUT  128
#define L_OUT  (L_IN - KW + 1)   // 8190
#define KDIM   (KW * C_INCH)     // 192

#define TILE_L  64
#define AROWS   (TILE_L + 2)     // 66
#define ASTRIDE 72               // 64 + 8 pad
#define TPB     2                // pipelined pair: prefetch t+1 under kloop+store of t
#define NGRID   (B_SZ * (L_IN / TILE_L) / TPB)   // 2048 blocks

// W fragment table: 8 n-tiles x 6 k-steps x 64 lanes, one short8 (16B) each.
#define WTAB_ELEMS (8 * 6 * 64)            // 3072 -> 49152 bytes

// packed fp32x2 -> bf16x2 (RNE, emits v_cvt_pk_bf16_f32)
__device__ __forceinline__ unsigned pk2(float a, float b) {
    __hip_bfloat162 h = __float22bfloat162_rn(make_float2(a, b));
    unsigned u;
    __builtin_memcpy(&u, &h, 4);
    return u;
}

// R7 prep: pre-swizzle w (fp32 [192][128]) into bf16 MFMA fragment layout.
// wtab[(nt*6 + s)*64 + lane] holds W[k = s*32 + q*8 + j][f = nt*16 + nl].
__global__ __launch_bounds__(256) void w_prep(const float* __restrict__ w,
                                              short8* __restrict__ wtab) {
    int id = blockIdx.x * 256 + threadIdx.x;
    if (id >= WTAB_ELEMS) return;
    int lane = id & 63;
    int s    = (id >> 6) % 6;
    int nt   = id / 384;
    int nl = lane & 15, q = lane >> 4;
    const float* __restrict__ wf = w + nt * 16 + nl;
    float t[8];
#pragma unroll
    for (int j = 0; j < 8; ++j) t[j] = wf[(s * 32 + q * 8 + j) * F_OUT];
    union { unsigned u[4]; short8 v; } hb;
    hb.u[0] = pk2(t[0], t[1]);
    hb.u[1] = pk2(t[2], t[3]);
    hb.u[2] = pk2(t[4], t[5]);
    hb.u[3] = pk2(t[6], t[7]);
    wtab[id] = hb.v;
}

// R8b: R8 with the nontemporal store fixed (builtin needs a clang ext-vector
// pointer, not HIP_vector_type float4*). Structure: wtab bfrag (12 coalesced
// 16B loads), swapped-operand MFMA (lane holds 4 consecutive f -> dwordx4
// epilogue), TPB=2 intra-block pipeline: tile t+1's global loads issued right
// AFTER the barrier so they stay in flight under tile t's kloop + epilogue.
// Output is write-once -> nontemporal stores keep the 134 MB stream from
// thrashing the per-XCD L2 that x-halo/wtab reads hit.
template <bool PREP>
__global__ __launch_bounds__(256, 4) void conv1d_mfma(const float* __restrict__ x,
                                                      const float* __restrict__ w,
                                                      const float* __restrict__ bias,
                                                      float* __restrict__ out,
                                                      const short8* __restrict__ wtab) {
    __shared__ short a_lds[2][AROWS * ASTRIDE];  // 2 x 9504 B

    const int tid  = threadIdx.x;
    const int lane = tid & 63;
    const int wave = tid >> 6;
    const int q    = lane >> 4;   // quad 0..3
    const int nl   = lane & 15;

    const int g      = blockIdx.x;
    const int b      = g >> 6;                     // 64 tile-pairs per batch row
    const int l_base = (g & 63) * (TPB * TILE_L);  // 128-row span per block

    // ---- B fragments: 12 coalesced 16B loads from the prepped table ----
    short8 bfrag[6][2];
    if (PREP) {
#pragma unroll
        for (int n = 0; n < 2; ++n)
#pragma unroll
            for (int s = 0; s < 6; ++s)
                bfrag[s][n] = wtab[(((wave * 2 + n) * 6 + s) << 6) + lane];
    } else {
        // fallback (workspace too small): build in-kernel
#pragma unroll
        for (int n = 0; n < 2; ++n) {
            const int f = (wave * 2 + n) * 16 + nl;
            const float* __restrict__ wf = w + f;
#pragma unroll
            for (int s = 0; s < 6; ++s) {
                float t[8];
#pragma unroll
                for (int j = 0; j < 8; ++j)
                    t[j] = wf[(s * 32 + q * 8 + j) * F_OUT];
                union { unsigned u[4]; short8 v; } hb;
                hb.u[0] = pk2(t[0], t[1]);
                hb.u[1] = pk2(t[2], t[3]);
                hb.u[2] = pk2(t[4], t[5]);
                hb.u[3] = pk2(t[6], t[7]);
                bfrag[s][n] = hb.v;
            }
        }
    }

    // bias: swapped C/D layout -> lane holds f = base + q*4 + r -> float4
    float4 bv[2];
#pragma unroll
    for (int n = 0; n < 2; ++n)
        bv[n] = *(const float4*)(bias + (wave * 2 + n) * 16 + q * 4);

    // ---- x-load for tile 0 ----
    float4 xv0[3], xv1[3];
    {
        const int l0 = l_base;
#pragma unroll
        for (int i = 0; i < 3; ++i) {
            int c = tid + 256 * i;
            if (c < AROWS * 8) {
                int p   = c >> 3;
                int col = (c & 7) * 8;
                int gl  = l0 + p;
                if (gl < L_IN) {
                    const float4* xp =
                        (const float4*)(x + ((size_t)b * L_IN + gl) * C_INCH + col);
                    xv0[i] = xp[0];
                    xv1[i] = xp[1];
                } else {
                    xv0[i] = make_float4(0.f, 0.f, 0.f, 0.f);
                    xv1[i] = xv0[i];
                }
            }
        }
    }

#pragma unroll
    for (int t = 0; t < TPB; ++t) {
        short* buf = a_lds[t & 1];

        // ---- convert + stage tile t ----
#pragma unroll
        for (int i = 0; i < 3; ++i) {
            int c = tid + 256 * i;
            if (c < AROWS * 8) {
                int p   = c >> 3;
                int col = (c & 7) * 8;
                union { unsigned u[4]; short8 v; } h;
                h.u[0] = pk2(xv0[i].x, xv0[i].y);
                h.u[1] = pk2(xv0[i].z, xv0[i].w);
                h.u[2] = pk2(xv1[i].x, xv1[i].y);
                h.u[3] = pk2(xv1[i].z, xv1[i].w);
                *(short8*)&buf[p * ASTRIDE + col] = h.v;
            }
        }
        __syncthreads();

        // ---- prefetch tile t+1 (after barrier; hides under kloop+epilogue) ----
        if (t + 1 < TPB) {
            const int l0n = l_base + (t + 1) * TILE_L;
#pragma unroll
            for (int i = 0; i < 3; ++i) {
                int c = tid + 256 * i;
                if (c < AROWS * 8) {
                    int p   = c >> 3;
                    int col = (c & 7) * 8;
                    int gl  = l0n + p;
                    if (gl < L_IN) {
                        const float4* xp =
                            (const float4*)(x + ((size_t)b * L_IN + gl) * C_INCH + col);
                        xv0[i] = xp[0];
                        xv1[i] = xp[1];
                    } else {
                        xv0[i] = make_float4(0.f, 0.f, 0.f, 0.f);
                        xv1[i] = xv0[i];
                    }
                }
            }
        }

        // ---- K-loop: 6 steps of 32; 4 m-tiles x 2 n-tiles per wave (swapped) ----
        floatx4 acc[4][2];
#pragma unroll
        for (int m = 0; m < 4; ++m)
#pragma unroll
            for (int n = 0; n < 2; ++n) acc[m][n] = (floatx4){0.f, 0.f, 0.f, 0.f};

#pragma unroll
        for (int s = 0; s < 6; ++s) {
#pragma unroll
            for (int m = 0; m < 4; ++m) {
                short8 af = *(const short8*)&buf[(m * 16 + nl + (s >> 1)) * ASTRIDE
                                                 + (s & 1) * 32 + q * 8];
#pragma unroll
                for (int n = 0; n < 2; ++n)
                    acc[m][n] = __builtin_amdgcn_mfma_f32_16x16x32_bf16(
                        bfrag[s][n], af, acc[m][n], 0, 0, 0);
            }
        }

        // ---- epilogue: lane(nl,q) holds f = base+q*4+r, l = l0+m*16+nl ----
        const int l0 = l_base + t * TILE_L;
#pragma unroll
        for (int n = 0; n < 2; ++n) {
            const int fb = (wave * 2 + n) * 16 + q * 4;
#pragma unroll
            for (int m = 0; m < 4; ++m) {
                const int l = l0 + m * 16 + nl;
                if (l < L_OUT) {
                    floatx4 v;
                    v[0] = acc[m][n][0] + bv[n].x;
                    v[1] = acc[m][n][1] + bv[n].y;
                    v[2] = acc[m][n][2] + bv[n].z;
                    v[3] = acc[m][n][3] + bv[n].w;
                    v[0] = v[0] > 0.f ? v[0] : 0.f;
                    v[1] = v[1] > 0.f ? v[1] : 0.f;
                    v[2] = v[2] > 0.f ? v[2] : 0.f;
                    v[3] = v[3] > 0.f ? v[3] : 0.f;
                    __builtin_nontemporal_store(
                        v, (floatx4*)(out + ((size_t)b * L_OUT + l) * F_OUT + fb));
                }
            }
        }
    }
}

extern "C" void kernel_launch(void* const* d_in, const int* in_sizes, int n_in,
                              void* d_out, int out_size, void* d_ws, size_t ws_size,
                              hipStream_t stream) {
    const float* x    = (const float*)d_in[0];
    const float* w    = (const float*)d_in[1];
    const float* bias = (const float*)d_in[2];
    float* out        = (float*)d_out;

    if (d_ws != nullptr && ws_size >= (size_t)WTAB_ELEMS * sizeof(short8)) {
        short8* wtab = (short8*)d_ws;
        w_prep<<<dim3((WTAB_ELEMS + 255) / 256), 256, 0, stream>>>(w, wtab);
        conv1d_mfma<true><<<dim3(NGRID), 256, 0, stream>>>(x, w, bias, out, wtab);
    } else {
        conv1d_mfma<false><<<dim3(NGRID), 256, 0, stream>>>(x, w, bias, out, nullptr);
    }
}

// Round 4
// 201.940 us; speedup vs baseline: 1.0479x; 1.0479x over previous
//
#include <hip/hip_runtime.h>
#include <hip/hip_bf16.h>

typedef __attribute__((ext_vector_type(8))) short short8;
typedef __attribute__((ext_vector_type(4))) float floatx4;

#define B_SZ   32
#define L_IN   8192
#define C_INCH 64
#define KW     3
#define F_OUT  128
#define L_OUT  (L_IN - KW + 1)   // 8190
#define KDIM   (KW * C_INCH)     // 192

#define TILE_L  64
#define AROWS   (TILE_L + 2)     // 66
#define ASTRIDE 72               // 64 + 8 pad
#define TPB     2                // pipelined pair: prefetch t+1 under kloop+store of t
#define NGRID   (B_SZ * (L_IN / TILE_L) / TPB)   // 2048 blocks

// W fragment table: 8 n-tiles x 6 k-steps x 64 lanes, one short8 (16B) each.
#define WTAB_ELEMS (8 * 6 * 64)            // 3072 -> 49152 bytes

// packed fp32x2 -> bf16x2 (RNE, emits v_cvt_pk_bf16_f32)
__device__ __forceinline__ unsigned pk2(float a, float b) {
    __hip_bfloat162 h = __float22bfloat162_rn(make_float2(a, b));
    unsigned u;
    __builtin_memcpy(&u, &h, 4);
    return u;
}

// R7 prep: pre-swizzle w (fp32 [192][128]) into bf16 MFMA fragment layout.
// wtab[(nt*6 + s)*64 + lane] holds W[k = s*32 + q*8 + j][f = nt*16 + nl].
__global__ __launch_bounds__(256) void w_prep(const float* __restrict__ w,
                                              short8* __restrict__ wtab) {
    int id = blockIdx.x * 256 + threadIdx.x;
    if (id >= WTAB_ELEMS) return;
    int lane = id & 63;
    int s    = (id >> 6) % 6;
    int nt   = id / 384;
    int nl = lane & 15, q = lane >> 4;
    const float* __restrict__ wf = w + nt * 16 + nl;
    float t[8];
#pragma unroll
    for (int j = 0; j < 8; ++j) t[j] = wf[(s * 32 + q * 8 + j) * F_OUT];
    union { unsigned u[4]; short8 v; } hb;
    hb.u[0] = pk2(t[0], t[1]);
    hb.u[1] = pk2(t[2], t[3]);
    hb.u[2] = pk2(t[4], t[5]);
    hb.u[3] = pk2(t[6], t[7]);
    wtab[id] = hb.v;
}

// R9: R8b pipeline at __launch_bounds__(256,3).
// R8b POST-MORTEM: at (256,4) the unified RF splits to 64 VGPR + AGPR;
// bfrag(48) + 24 live prefetch float4 regs spilled -> WRITE_SIZE 142.6->190 MB
// (+47 MB scratch), conv 57->80 us. Same failure R5 hit. At (256,3) the
// budget is ~170 unified regs (R0 ran this shape at 84 VGPR, no spill).
// Structure: wtab bfrag (12 coalesced 16B loads), swapped-operand MFMA
// (lane holds 4 consecutive f -> dwordx4 epilogue), TPB=2: tile t+1's global
// loads issued right AFTER the barrier so they stay in flight under tile t's
// kloop + epilogue. NT stores on the write-once 134 MB output stream.
template <bool PREP>
__global__ __launch_bounds__(256, 3) void conv1d_mfma(const float* __restrict__ x,
                                                      const float* __restrict__ w,
                                                      const float* __restrict__ bias,
                                                      float* __restrict__ out,
                                                      const short8* __restrict__ wtab) {
    __shared__ short a_lds[2][AROWS * ASTRIDE];  // 2 x 9504 B

    const int tid  = threadIdx.x;
    const int lane = tid & 63;
    const int wave = tid >> 6;
    const int q    = lane >> 4;   // quad 0..3
    const int nl   = lane & 15;

    const int g      = blockIdx.x;
    const int b      = g >> 6;                     // 64 tile-pairs per batch row
    const int l_base = (g & 63) * (TPB * TILE_L);  // 128-row span per block

    // ---- B fragments: 12 coalesced 16B loads from the prepped table ----
    short8 bfrag[6][2];
    if (PREP) {
#pragma unroll
        for (int n = 0; n < 2; ++n)
#pragma unroll
            for (int s = 0; s < 6; ++s)
                bfrag[s][n] = wtab[(((wave * 2 + n) * 6 + s) << 6) + lane];
    } else {
        // fallback (workspace too small): build in-kernel
#pragma unroll
        for (int n = 0; n < 2; ++n) {
            const int f = (wave * 2 + n) * 16 + nl;
            const float* __restrict__ wf = w + f;
#pragma unroll
            for (int s = 0; s < 6; ++s) {
                float t[8];
#pragma unroll
                for (int j = 0; j < 8; ++j)
                    t[j] = wf[(s * 32 + q * 8 + j) * F_OUT];
                union { unsigned u[4]; short8 v; } hb;
                hb.u[0] = pk2(t[0], t[1]);
                hb.u[1] = pk2(t[2], t[3]);
                hb.u[2] = pk2(t[4], t[5]);
                hb.u[3] = pk2(t[6], t[7]);
                bfrag[s][n] = hb.v;
            }
        }
    }

    // bias: swapped C/D layout -> lane holds f = base + q*4 + r -> float4
    float4 bv[2];
#pragma unroll
    for (int n = 0; n < 2; ++n)
        bv[n] = *(const float4*)(bias + (wave * 2 + n) * 16 + q * 4);

    // ---- x-load for tile 0 ----
    float4 xv0[3], xv1[3];
    {
        const int l0 = l_base;
#pragma unroll
        for (int i = 0; i < 3; ++i) {
            int c = tid + 256 * i;
            if (c < AROWS * 8) {
                int p   = c >> 3;
                int col = (c & 7) * 8;
                int gl  = l0 + p;
                if (gl < L_IN) {
                    const float4* xp =
                        (const float4*)(x + ((size_t)b * L_IN + gl) * C_INCH + col);
                    xv0[i] = xp[0];
                    xv1[i] = xp[1];
                } else {
                    xv0[i] = make_float4(0.f, 0.f, 0.f, 0.f);
                    xv1[i] = xv0[i];
                }
            }
        }
    }

#pragma unroll
    for (int t = 0; t < TPB; ++t) {
        short* buf = a_lds[t & 1];

        // ---- convert + stage tile t ----
#pragma unroll
        for (int i = 0; i < 3; ++i) {
            int c = tid + 256 * i;
            if (c < AROWS * 8) {
                int p   = c >> 3;
                int col = (c & 7) * 8;
                union { unsigned u[4]; short8 v; } h;
                h.u[0] = pk2(xv0[i].x, xv0[i].y);
                h.u[1] = pk2(xv0[i].z, xv0[i].w);
                h.u[2] = pk2(xv1[i].x, xv1[i].y);
                h.u[3] = pk2(xv1[i].z, xv1[i].w);
                *(short8*)&buf[p * ASTRIDE + col] = h.v;
            }
        }
        __syncthreads();

        // ---- prefetch tile t+1 (after barrier; hides under kloop+epilogue) ----
        if (t + 1 < TPB) {
            const int l0n = l_base + (t + 1) * TILE_L;
#pragma unroll
            for (int i = 0; i < 3; ++i) {
                int c = tid + 256 * i;
                if (c < AROWS * 8) {
                    int p   = c >> 3;
                    int col = (c & 7) * 8;
                    int gl  = l0n + p;
                    if (gl < L_IN) {
                        const float4* xp =
                            (const float4*)(x + ((size_t)b * L_IN + gl) * C_INCH + col);
                        xv0[i] = xp[0];
                        xv1[i] = xp[1];
                    } else {
                        xv0[i] = make_float4(0.f, 0.f, 0.f, 0.f);
                        xv1[i] = xv0[i];
                    }
                }
            }
        }

        // ---- K-loop: 6 steps of 32; 4 m-tiles x 2 n-tiles per wave (swapped) ----
        floatx4 acc[4][2];
#pragma unroll
        for (int m = 0; m < 4; ++m)
#pragma unroll
            for (int n = 0; n < 2; ++n) acc[m][n] = (floatx4){0.f, 0.f, 0.f, 0.f};

#pragma unroll
        for (int s = 0; s < 6; ++s) {
#pragma unroll
            for (int m = 0; m < 4; ++m) {
                short8 af = *(const short8*)&buf[(m * 16 + nl + (s >> 1)) * ASTRIDE
                                                 + (s & 1) * 32 + q * 8];
#pragma unroll
                for (int n = 0; n < 2; ++n)
                    acc[m][n] = __builtin_amdgcn_mfma_f32_16x16x32_bf16(
                        bfrag[s][n], af, acc[m][n], 0, 0, 0);
            }
        }

        // ---- epilogue: lane(nl,q) holds f = base+q*4+r, l = l0+m*16+nl ----
        const int l0 = l_base + t * TILE_L;
#pragma unroll
        for (int n = 0; n < 2; ++n) {
            const int fb = (wave * 2 + n) * 16 + q * 4;
#pragma unroll
            for (int m = 0; m < 4; ++m) {
                const int l = l0 + m * 16 + nl;
                if (l < L_OUT) {
                    floatx4 v;
                    v[0] = acc[m][n][0] + bv[n].x;
                    v[1] = acc[m][n][1] + bv[n].y;
                    v[2] = acc[m][n][2] + bv[n].z;
                    v[3] = acc[m][n][3] + bv[n].w;
                    v[0] = v[0] > 0.f ? v[0] : 0.f;
                    v[1] = v[1] > 0.f ? v[1] : 0.f;
                    v[2] = v[2] > 0.f ? v[2] : 0.f;
                    v[3] = v[3] > 0.f ? v[3] : 0.f;
                    __builtin_nontemporal_store(
                        v, (floatx4*)(out + ((size_t)b * L_OUT + l) * F_OUT + fb));
                }
            }
        }
    }
}

extern "C" void kernel_launch(void* const* d_in, const int* in_sizes, int n_in,
                              void* d_out, int out_size, void* d_ws, size_t ws_size,
                              hipStream_t stream) {
    const float* x    = (const float*)d_in[0];
    const float* w    = (const float*)d_in[1];
    const float* bias = (const float*)d_in[2];
    float* out        = (float*)d_out;

    if (d_ws != nullptr && ws_size >= (size_t)WTAB_ELEMS * sizeof(short8)) {
        short8* wtab = (short8*)d_ws;
        w_prep<<<dim3((WTAB_ELEMS + 255) / 256), 256, 0, stream>>>(w, wtab);
        conv1d_mfma<true><<<dim3(NGRID), 256, 0, stream>>>(x, w, bias, out, wtab);
    } else {
        conv1d_mfma<false><<<dim3(NGRID), 256, 0, stream>>>(x, w, bias, out, nullptr);
    }
}

// Round 5
// 200.510 us; speedup vs baseline: 1.0554x; 1.0071x over previous
//
#include <hip/hip_runtime.h>
#include <hip/hip_bf16.h>

typedef __attribute__((ext_vector_type(8))) short short8;
typedef __attribute__((ext_vector_type(4))) float floatx4;

#define B_SZ   32
#define L_IN   8192
#define C_INCH 64
#define KW     3
#define F_OUT  128
#define L_OUT  (L_IN - KW + 1)   // 8190
#define KDIM   (KW * C_INCH)     // 192

#define TILE_L  64
#define AROWS   (TILE_L + 2)     // 66
#define ASTRIDE 72               // 64 + 8 pad
#define NGRID   (B_SZ * (L_IN / TILE_L))   // 4096 blocks, TPB=1

// W fragment table: 8 n-tiles x 6 k-steps x 64 lanes, one short8 (16B) each.
#define WTAB_ELEMS (8 * 6 * 64)            // 3072 -> 49152 bytes

// packed fp32x2 -> bf16x2 (RNE, emits v_cvt_pk_bf16_f32)
__device__ __forceinline__ unsigned pk2(float a, float b) {
    __hip_bfloat162 h = __float22bfloat162_rn(make_float2(a, b));
    unsigned u;
    __builtin_memcpy(&u, &h, 4);
    return u;
}

// R7 prep: pre-swizzle w (fp32 [192][128]) into bf16 MFMA fragment layout.
// wtab[(nt*6 + s)*64 + lane] holds W[k = s*32 + q*8 + j][f = nt*16 + nl].
__global__ __launch_bounds__(256) void w_prep(const float* __restrict__ w,
                                              short8* __restrict__ wtab) {
    int id = blockIdx.x * 256 + threadIdx.x;
    if (id >= WTAB_ELEMS) return;
    int lane = id & 63;
    int s    = (id >> 6) % 6;
    int nt   = id / 384;
    int nl = lane & 15, q = lane >> 4;
    const float* __restrict__ wf = w + nt * 16 + nl;
    float t[8];
#pragma unroll
    for (int j = 0; j < 8; ++j) t[j] = wf[(s * 32 + q * 8 + j) * F_OUT];
    union { unsigned u[4]; short8 v; } hb;
    hb.u[0] = pk2(t[0], t[1]);
    hb.u[1] = pk2(t[2], t[3]);
    hb.u[2] = pk2(t[4], t[5]);
    hb.u[3] = pk2(t[6], t[7]);
    wtab[id] = hb.v;
}

// R10: revert to R1 structure (TPB=1, grid 4096, occ 4) — the best measured
// config (~60 us conv) — with ONE delta: nontemporal stores on the write-once
// output stream.
// R9 POST-MORTEM: TPB=2 @ (256,3) ran unspilled but conv ~70 us vs R1's ~60:
// 4-blocks/CU cross-block stagger hides more latency than the intra-block
// prefetch at 3 blocks/CU, and 4096 thin blocks stagger finer than 2048 fat
// ones. Occupancy > pipelining here; TPB experiments closed.
// NT mechanism: 131 KB/block of never-re-read output would otherwise cycle
// through the 4 MB per-XCD L2 that x-halo + wtab reads want to hit.
template <bool PREP>
__global__ __launch_bounds__(256, 4) void conv1d_mfma(const float* __restrict__ x,
                                                      const float* __restrict__ w,
                                                      const float* __restrict__ bias,
                                                      float* __restrict__ out,
                                                      const short8* __restrict__ wtab) {
    __shared__ short a_lds[AROWS * ASTRIDE];  // 9504 B, single buffer

    const int tid  = threadIdx.x;
    const int lane = tid & 63;
    const int wave = tid >> 6;
    const int q    = lane >> 4;   // quad 0..3
    const int nl   = lane & 15;

    const int g  = blockIdx.x;
    const int b  = g >> 7;              // L_IN/TILE_L = 128 tiles per batch row
    const int l0 = (g & 127) * TILE_L;

    // ---- B fragments: 12 coalesced 16B loads from the prepped table ----
    short8 bfrag[6][2];
    if (PREP) {
#pragma unroll
        for (int n = 0; n < 2; ++n)
#pragma unroll
            for (int s = 0; s < 6; ++s)
                bfrag[s][n] = wtab[(((wave * 2 + n) * 6 + s) << 6) + lane];
    } else {
        // fallback (workspace too small): build in-kernel
#pragma unroll
        for (int n = 0; n < 2; ++n) {
            const int f = (wave * 2 + n) * 16 + nl;
            const float* __restrict__ wf = w + f;
#pragma unroll
            for (int s = 0; s < 6; ++s) {
                float t[8];
#pragma unroll
                for (int j = 0; j < 8; ++j)
                    t[j] = wf[(s * 32 + q * 8 + j) * F_OUT];
                union { unsigned u[4]; short8 v; } hb;
                hb.u[0] = pk2(t[0], t[1]);
                hb.u[1] = pk2(t[2], t[3]);
                hb.u[2] = pk2(t[4], t[5]);
                hb.u[3] = pk2(t[6], t[7]);
                bfrag[s][n] = hb.v;
            }
        }
    }

    // bias: swapped C/D layout -> lane holds f = base + q*4 + r -> float4
    float4 bv[2];
#pragma unroll
    for (int n = 0; n < 2; ++n)
        bv[n] = *(const float4*)(bias + (wave * 2 + n) * 16 + q * 4);

    // ---- stage x tile: fp32 -> bf16 into LDS ----
#pragma unroll
    for (int i = 0; i < 3; ++i) {
        int c = tid + 256 * i;
        if (c < AROWS * 8) {
            int p   = c >> 3;
            int col = (c & 7) * 8;
            int gl  = l0 + p;
            float4 v0, v1;
            if (gl < L_IN) {
                const float4* xp =
                    (const float4*)(x + ((size_t)b * L_IN + gl) * C_INCH + col);
                v0 = xp[0];
                v1 = xp[1];
            } else {
                v0 = make_float4(0.f, 0.f, 0.f, 0.f);
                v1 = v0;
            }
            union { unsigned u[4]; short8 v; } h;
            h.u[0] = pk2(v0.x, v0.y);
            h.u[1] = pk2(v0.z, v0.w);
            h.u[2] = pk2(v1.x, v1.y);
            h.u[3] = pk2(v1.z, v1.w);
            *(short8*)&a_lds[p * ASTRIDE + col] = h.v;
        }
    }
    __syncthreads();

    // ---- K-loop: 6 steps of 32; 4 m-tiles x 2 n-tiles per wave (swapped) ----
    floatx4 acc[4][2];
#pragma unroll
    for (int m = 0; m < 4; ++m)
#pragma unroll
        for (int n = 0; n < 2; ++n) acc[m][n] = (floatx4){0.f, 0.f, 0.f, 0.f};

#pragma unroll
    for (int s = 0; s < 6; ++s) {
#pragma unroll
        for (int m = 0; m < 4; ++m) {
            short8 af = *(const short8*)&a_lds[(m * 16 + nl + (s >> 1)) * ASTRIDE
                                               + (s & 1) * 32 + q * 8];
#pragma unroll
            for (int n = 0; n < 2; ++n)
                acc[m][n] = __builtin_amdgcn_mfma_f32_16x16x32_bf16(
                    bfrag[s][n], af, acc[m][n], 0, 0, 0);
        }
    }

    // ---- epilogue: lane(nl,q) holds f = base+q*4+r (r=0..3), l = l0+m*16+nl
    //      -> one NT float4 store per (m,n) ----
#pragma unroll
    for (int n = 0; n < 2; ++n) {
        const int fb = (wave * 2 + n) * 16 + q * 4;
#pragma unroll
        for (int m = 0; m < 4; ++m) {
            const int l = l0 + m * 16 + nl;
            if (l < L_OUT) {
                floatx4 v;
                v[0] = acc[m][n][0] + bv[n].x;
                v[1] = acc[m][n][1] + bv[n].y;
                v[2] = acc[m][n][2] + bv[n].z;
                v[3] = acc[m][n][3] + bv[n].w;
                v[0] = v[0] > 0.f ? v[0] : 0.f;
                v[1] = v[1] > 0.f ? v[1] : 0.f;
                v[2] = v[2] > 0.f ? v[2] : 0.f;
                v[3] = v[3] > 0.f ? v[3] : 0.f;
                __builtin_nontemporal_store(
                    v, (floatx4*)(out + ((size_t)b * L_OUT + l) * F_OUT + fb));
            }
        }
    }
}

extern "C" void kernel_launch(void* const* d_in, const int* in_sizes, int n_in,
                              void* d_out, int out_size, void* d_ws, size_t ws_size,
                              hipStream_t stream) {
    const float* x    = (const float*)d_in[0];
    const float* w    = (const float*)d_in[1];
    const float* bias = (const float*)d_in[2];
    float* out        = (float*)d_out;

    if (d_ws != nullptr && ws_size >= (size_t)WTAB_ELEMS * sizeof(short8)) {
        short8* wtab = (short8*)d_ws;
        w_prep<<<dim3((WTAB_ELEMS + 255) / 256), 256, 0, stream>>>(w, wtab);
        conv1d_mfma<true><<<dim3(NGRID), 256, 0, stream>>>(x, w, bias, out, wtab);
    } else {
        conv1d_mfma<false><<<dim3(NGRID), 256, 0, stream>>>(x, w, bias, out, nullptr);
    }
}